// Round 3
// baseline (122.516 us; speedup 1.0000x reference)
//
#include <hip/hip_runtime.h>
#include <stdint.h>

#define IN_DIM 2048
#define OUT_DIM 2048
#define BATCH 4096
#define KDIM (2 * IN_DIM)   // 4096
#define KROWB (KDIM * 2)    // 8192 bytes per bf16 row
#define KH 2048             // K-half (split-K=2)
#define NTT 32              // K-tiles of 64 per half
#define BN_EPS 1e-5f

typedef __attribute__((ext_vector_type(8))) short bf16x8;
typedef __attribute__((ext_vector_type(4))) float f32x4;

__device__ __forceinline__ unsigned short f2bf(float f) {
  union { float f; unsigned u; } v; v.f = f;
  unsigned r = v.u + 0x7FFFu + ((v.u >> 16) & 1u);  // RNE
  return (unsigned short)(r >> 16);
}

// K1a: A = [wavelet(x) | x] bf16, row-major (BATCH x KDIM)
__global__ void prep_act(const float* __restrict__ x,
                         const float* __restrict__ scale,
                         const float* __restrict__ translate,
                         unsigned short* __restrict__ A) {
  int e = (blockIdx.x * 256 + threadIdx.x) * 4;
  int b = e / IN_DIM;
  int i = e % IN_DIM;
  float4 xv = *(const float4*)(x + e);
  float4 sv = *(const float4*)(scale + i);
  float4 tv = *(const float4*)(translate + i);
  const float c = 0.7511255444649425f;  // pi^-0.25
  float u0 = (xv.x - tv.x) / fmaxf(sv.x, 1e-3f);
  float u1 = (xv.y - tv.y) / fmaxf(sv.y, 1e-3f);
  float u2 = (xv.z - tv.z) / fmaxf(sv.z, 1e-3f);
  float u3 = (xv.w - tv.w) / fmaxf(sv.w, 1e-3f);
  ushort4 wv, xb;
  wv.x = f2bf(c * __cosf(3.0f * u0) * __expf(-0.5f * u0 * u0));
  wv.y = f2bf(c * __cosf(3.0f * u1) * __expf(-0.5f * u1 * u1));
  wv.z = f2bf(c * __cosf(3.0f * u2) * __expf(-0.5f * u2 * u2));
  wv.w = f2bf(c * __cosf(3.0f * u3) * __expf(-0.5f * u3 * u3));
  xb.x = f2bf(xv.x); xb.y = f2bf(xv.y); xb.z = f2bf(xv.z); xb.w = f2bf(xv.w);
  *(ushort4*)(A + (size_t)b * KDIM + i) = wv;
  *(ushort4*)(A + (size_t)b * KDIM + IN_DIM + i) = xb;
}

// K1b: W = [wave_weight | 0.3*base_weight] bf16, row-major (OUT_DIM x KDIM)
__global__ void prep_w(const float* __restrict__ ww,
                       const float* __restrict__ bw,
                       unsigned short* __restrict__ W) {
  int e = (blockIdx.x * 256 + threadIdx.x) * 4;
  int o = e / IN_DIM;
  int k = e % IN_DIM;
  float4 a = *(const float4*)(ww + e);
  float4 b = *(const float4*)(bw + e);
  ushort4 wa, wb;
  wa.x = f2bf(a.x); wa.y = f2bf(a.y); wa.z = f2bf(a.z); wa.w = f2bf(a.w);
  wb.x = f2bf(0.3f * b.x); wb.y = f2bf(0.3f * b.y);
  wb.z = f2bf(0.3f * b.z); wb.w = f2bf(0.3f * b.w);
  *(ushort4*)(W + (size_t)o * KDIM + k) = wa;
  *(ushort4*)(W + (size_t)o * KDIM + IN_DIM + k) = wb;
}

// ------- split-K 256x256 GEMM, m201 geometry: 8 waves of 128x64, BK=64 -------
// LDS per parity (64K): A0=0 (rows 0-127), A1=16384, B0=32768, B1=49152.
// Stage ops (2 GLDS each), 1/phase: ph1->B1[u+1], ph2->A0[u+1], ph3->A1[u+1],
// ph4->B0[u+2]. Need-based counted waits: vmcnt(4) at ph1-end and ph4-end.

#define GLDS(gp, lo) __builtin_amdgcn_global_load_lds( \
    (const __attribute__((address_space(1))) void*)(gp), \
    (__attribute__((address_space(3))) void*)(lds + (lo) + ldsl), 16, 0, 0)

#define STG(u_, gp_, t_) do { \
  GLDS((gp_) + (size_t)(t_) * 128, (u_)); \
  GLDS((gp_) + (size_t)64 * KROWB + (size_t)(t_) * 128, (u_) + 8192); \
} while (0)

#define LDA4(mh, ss) do { \
  af[0] = *(const bf16x8*)(lds + P + rA + ((mh) * 4 + 0) * 2048 + (ss)); \
  af[1] = *(const bf16x8*)(lds + P + rA + ((mh) * 4 + 1) * 2048 + (ss)); \
  af[2] = *(const bf16x8*)(lds + P + rA + ((mh) * 4 + 2) * 2048 + (ss)); \
  af[3] = *(const bf16x8*)(lds + P + rA + ((mh) * 4 + 3) * 2048 + (ss)); \
} while (0)

#define LDB4(dst, ss) do { \
  dst[0] = *(const bf16x8*)(lds + P + rB + 0 * 2048 + (ss)); \
  dst[1] = *(const bf16x8*)(lds + P + rB + 1 * 2048 + (ss)); \
  dst[2] = *(const bf16x8*)(lds + P + rB + 2 * 2048 + (ss)); \
  dst[3] = *(const bf16x8*)(lds + P + rB + 3 * 2048 + (ss)); \
} while (0)

#define MM16(mh, bfr) do { \
  __builtin_amdgcn_s_setprio(1); \
  _Pragma("unroll") for (int i2 = 0; i2 < 4; ++i2) \
  _Pragma("unroll") for (int j2 = 0; j2 < 4; ++j2) \
    acc[(mh) * 4 + i2][j2] = __builtin_amdgcn_mfma_f32_16x16x32_bf16( \
        af[i2], bfr[j2], acc[(mh) * 4 + i2][j2], 0, 0, 0); \
  __builtin_amdgcn_s_setprio(0); \
} while (0)

#define LGKM0() asm volatile("s_waitcnt lgkmcnt(0)" ::: "memory")
#define VMW4()  asm volatile("s_waitcnt vmcnt(4)" ::: "memory")
#define VMW0()  asm volatile("s_waitcnt vmcnt(0)" ::: "memory")
#define BAR()   do { asm volatile("" ::: "memory"); __builtin_amdgcn_s_barrier(); \
                     asm volatile("" ::: "memory"); } while (0)

#define KTILE(u, DOST, DOST2, TAILB) do { \
  const int P = ((u) & 1) << 16; \
  const int Q = P ^ 65536; \
  LDA4(0, s0); LDB4(b0, s0); \
  if (DOST) STG(Q + 49152, bS1, (u) + 1); \
  BAR(); MM16(0, b0); LGKM0(); VMW4(); BAR(); \
  LDA4(1, s0); \
  if (DOST) STG(Q + 0, aS0, (u) + 1); \
  BAR(); MM16(1, b0); LGKM0(); BAR(); \
  LDA4(0, s1); LDB4(b1, s1); \
  if (DOST) STG(Q + 16384, aS1, (u) + 1); \
  BAR(); MM16(0, b1); LGKM0(); BAR(); \
  LDA4(1, s1); \
  if (DOST2) STG(P + 32768, bS0, (u) + 2); \
  BAR(); MM16(1, b1); LGKM0(); TAILB; BAR(); \
} while (0)

__global__ __launch_bounds__(512, 2) void gemm256(
    const unsigned short* __restrict__ A,
    const unsigned short* __restrict__ W,
    float* __restrict__ P0, float* __restrict__ P1) {
  __shared__ char lds[131072];
  const int tid = threadIdx.x;
  const int lane = tid & 63;
  const int wave = tid >> 6;
  const int wm = wave >> 2;   // 0..1 -> 128-row M half
  const int wn = wave & 3;    // 0..3 -> 64-col N quarter

  // XCD-aware bijective swizzle (256 blocks, %8==0); sw = [kz:1][m:4][n:3]
  const int sw = ((blockIdx.x & 7) << 5) | (blockIdx.x >> 3);
  const int kz = sw >> 7;
  const int brow = ((sw >> 3) & 15) * 256;
  const int bcol = (sw & 7) * 256;
  const size_t kb = (size_t)kz * (KH * 2);  // byte offset of K-half

  // staging: thread -> row tid>>3 (0..63), pre-swizzled 16B slot
  const int srow = tid >> 3;
  const int gc16 = (tid & 7) ^ (srow & 7);
  const char* aS0 = (const char*)A + (size_t)(brow + srow) * KROWB + kb + gc16 * 16;
  const char* aS1 = aS0 + (size_t)128 * KROWB;
  const char* bS0 = (const char*)W + (size_t)(bcol + srow) * KROWB + kb + gc16 * 16;
  const char* bS1 = bS0 + (size_t)128 * KROWB;
  const int ldsl = wave * 1024;  // + lane*16 implicit in global_load_lds

  // fragment read offsets (swizzled): byte = row*128 + ((c16 ^ (row&7))<<4)
  const int rA = (wm * 128 + (lane & 15)) * 128;
  const int rB = 32768 + (wn * 64 + (lane & 15)) * 128;
  const int s0 = (((lane >> 4)    ) ^ (lane & 7)) << 4;  // kk=0
  const int s1 = ((4 + (lane >> 4)) ^ (lane & 7)) << 4;  // kk=1

  f32x4 acc[8][4];
#pragma unroll
  for (int m = 0; m < 8; ++m)
#pragma unroll
    for (int n = 0; n < 4; ++n)
      acc[m][n] = (f32x4){0.f, 0.f, 0.f, 0.f};
  bf16x8 af[4], b0[4], b1[4];

  // prologue FIFO: B0[0], B1[0], A0[0], A1[0], B0[1]  (10 loads)
  STG(32768, bS0, 0); STG(49152, bS1, 0); STG(0, aS0, 0); STG(16384, aS1, 0);
  STG(65536 + 32768, bS0, 1);
  VMW4(); BAR();

  for (int u = 0; u < NTT - 2; ++u)
    KTILE(u, 1, 1, VMW4());
  KTILE(NTT - 2, 1, 0, VMW0());
  KTILE(NTT - 1, 0, 0, VMW0());

  float* Pz = kz ? P1 : P0;
  const int r0 = brow + wm * 128 + (lane >> 4) * 4;
  const int c0 = bcol + wn * 64 + (lane & 15);
#pragma unroll
  for (int m = 0; m < 8; ++m)
#pragma unroll
    for (int n = 0; n < 4; ++n)
#pragma unroll
      for (int j = 0; j < 4; ++j)
        Pz[(size_t)(r0 + m * 16 + j) * OUT_DIM + (c0 + n * 16)] = acc[m][n][j];
}

// K3a: fused partial-add + per-column stats. Y (=P0=d_out) += P1, stats.
__global__ void colstats2(const float* __restrict__ P1,
                          float* __restrict__ Y,
                          float* __restrict__ sums, float* __restrict__ sqs) {
  int col = (blockIdx.x & 7) * 256 + threadIdx.x;
  int r0 = (blockIdx.x >> 3) * 128;
  float s = 0.f, q = 0.f;
  for (int r = 0; r < 128; ++r) {
    size_t idx = (size_t)(r0 + r) * OUT_DIM + col;
    float v = Y[idx] + P1[idx];
    Y[idx] = v;
    s += v;
    q += v * v;
  }
  atomicAdd(&sums[col], s);
  atomicAdd(&sqs[col], q);
}

// K3b: in-place batchnorm on Y
__global__ void bnorm(float* __restrict__ Y,
                      const float* __restrict__ sums, const float* __restrict__ sqs,
                      const float* __restrict__ gamma, const float* __restrict__ beta) {
  int e = (blockIdx.x * 256 + threadIdx.x) * 4;
  int c = e % OUT_DIM;
  float4 y = *(float4*)(Y + e);
  float4 s = *(const float4*)(sums + c);
  float4 q = *(const float4*)(sqs + c);
  float4 g = *(const float4*)(gamma + c);
  float4 bb = *(const float4*)(beta + c);
  const float invB = 1.0f / (float)BATCH;
  float m0 = s.x * invB, m1 = s.y * invB, m2 = s.z * invB, m3 = s.w * invB;
  float i0 = rsqrtf(q.x * invB - m0 * m0 + BN_EPS);
  float i1 = rsqrtf(q.y * invB - m1 * m1 + BN_EPS);
  float i2 = rsqrtf(q.z * invB - m2 * m2 + BN_EPS);
  float i3 = rsqrtf(q.w * invB - m3 * m3 + BN_EPS);
  y.x = g.x * (y.x - m0) * i0 + bb.x;
  y.y = g.y * (y.y - m1) * i1 + bb.y;
  y.z = g.z * (y.z - m2) * i2 + bb.z;
  y.w = g.w * (y.w - m3) * i3 + bb.w;
  *(float4*)(Y + e) = y;
}

extern "C" void kernel_launch(void* const* d_in, const int* in_sizes, int n_in,
                              void* d_out, int out_size, void* d_ws, size_t ws_size,
                              hipStream_t stream) {
  const float* x         = (const float*)d_in[0];
  const float* scale     = (const float*)d_in[1];
  const float* translate = (const float*)d_in[2];
  const float* ww        = (const float*)d_in[3];
  const float* bw        = (const float*)d_in[4];
  const float* gamma     = (const float*)d_in[5];
  const float* beta      = (const float*)d_in[6];
  float* out = (float*)d_out;

  char* ws = (char*)d_ws;
  unsigned short* A = (unsigned short*)ws;                 // 33,554,432 B
  unsigned short* W = (unsigned short*)(ws + 33554432);    // 16,777,216 B
  float* P1   = (float*)(ws + 50331648);                   // 33,554,432 B
  float* sums = (float*)(ws + 83886080);
  float* sqs  = sums + OUT_DIM;

  hipMemsetAsync(sums, 0, 2 * OUT_DIM * sizeof(float), stream);
  prep_act<<<(BATCH * IN_DIM) / 1024, 256, 0, stream>>>(x, scale, translate, A);
  prep_w<<<(OUT_DIM * IN_DIM) / 1024, 256, 0, stream>>>(ww, bw, W);
  gemm256<<<256, 512, 0, stream>>>(A, W, out, P1);
  colstats2<<<256, 256, 0, stream>>>(P1, out, sums, sqs);
  bnorm<<<(BATCH * OUT_DIM) / 1024, 256, 0, stream>>>(out, sums, sqs, gamma, beta);
}